// Round 4
// baseline (53.576 us; speedup 1.0000x reference)
//
#include <hip/hip_runtime.h>

#define NW 12
#define DIM 4096
#define NL 4
#define NGATE 48
#define NOUT 4
#define TPB 256

typedef float f32x2 __attribute__((ext_vector_type(2)));

// ======================= constexpr GF(2) machinery =======================
// State in registers: phys y = k*256 + t (k = 4 reg bits, t = 8 thread bits).
// Per group g (4 gates), basis B_g (storage = B_g(phys)):
//   B_g(e_{8+i}) = m_i          (gate pair masks -> reg bits)
//   cols(B_g) ⊥ rm_i except 8+i (gate role == reg bit, no selects)
// Exchange: write linear amp[k*256+t], read amp[base(t) ^ RK16[k]] with
// base(t) = XOR of RCOL[j] over t-bits. Conflict-free iff the lane-bit
// columns' low nibbles (f32x2 units, 16 bank-pairs) have rank 4 -> planner
// pins 4 nibble-independent columns into lane slots 0..3.

constexpr int pcnt(unsigned x){ int c=0; for(int i=0;i<12;++i) c+=(x>>i)&1; return c; }
constexpr unsigned ring_fwd(unsigned x,int r){
  for(int w=0;w<NW;++w){ int c=NW-1-w,t=NW-1-((w+r)%NW); x^=((x>>c)&1u)<<t; } return x;
}
constexpr unsigned ring_rev(unsigned x,int r){
  for(int w=NW-1;w>=0;--w){ int c=NW-1-w,t=NW-1-((w+r)%NW); x^=((x>>c)&1u)<<t; } return x;
}

struct Mat { unsigned col[12]; };
constexpr unsigned apply_cols(const Mat&M, unsigned v){
  unsigned r=0; for(int j=0;j<12;++j) if((v>>j)&1u) r^=M.col[j]; return r;
}
constexpr unsigned apply_rows(const unsigned* rows, unsigned v){
  unsigned r=0; for(int i=0;i<12;++i) r|=(unsigned)(pcnt(rows[i]&v)&1)<<i; return r;
}
constexpr bool invert_rows(const Mat&M, unsigned* ri_out){
  unsigned rb[12], ri[12];
  for(int i=0;i<12;++i){ unsigned r=0; for(int j=0;j<12;++j) r|=((M.col[j]>>i)&1u)<<j; rb[i]=r; ri[i]=1u<<i; }
  for(int c=0;c<12;++c){
    int piv=-1; for(int r=c;r<12;++r) if((rb[r]>>c)&1u){piv=r;break;}
    if(piv<0) return false;
    unsigned t=rb[c]; rb[c]=rb[piv]; rb[piv]=t; t=ri[c]; ri[c]=ri[piv]; ri[piv]=t;
    for(int r=0;r<12;++r) if(r!=c&&((rb[r]>>c)&1u)){ rb[r]^=rb[c]; ri[r]^=ri[c]; }
  }
  for(int i=0;i<12;++i) ri_out[i]=ri[i];
  return true;
}
constexpr int nullspace4(const unsigned* A0, unsigned* out){
  unsigned A[4]; for(int i=0;i<4;++i) A[i]=A0[i];
  int rank=0; int pivc[4]={-1,-1,-1,-1};
  for(int c=0;c<12&&rank<4;++c){
    int piv=-1; for(int r=rank;r<4;++r) if((A[r]>>c)&1u){piv=r;break;}
    if(piv<0) continue;
    unsigned t=A[rank];A[rank]=A[piv];A[piv]=t;
    for(int r=0;r<4;++r) if(r!=rank&&((A[r]>>c)&1u)) A[r]^=A[rank];
    pivc[rank]=c; ++rank;
  }
  if(rank!=4) return -1;
  bool ispiv[12]={};
  for(int r=0;r<4;++r) ispiv[pivc[r]]=true;
  int cnt=0;
  for(int f=0;f<12;++f) if(!ispiv[f]){
    unsigned v=1u<<f;
    for(int r=0;r<4;++r) if((A[r]>>f)&1u) v|=1u<<pivc[r];
    out[cnt++]=v;
  }
  return cnt;
}
struct Ech { unsigned r[12]; int lead[12]; int n; };
constexpr int msbp(unsigned x){ for(int i=11;i>=0;--i) if((x>>i)&1u) return i; return -1; }
constexpr unsigned ech_red(const Ech&e, unsigned v){
  int mv=msbp(v);
  for(int i=0;i<e.n&&v;++i) if(e.lead[i]==mv){ v^=e.r[i]; mv=msbp(v); }
  return v;
}
constexpr void ech_add(Ech&e, unsigned v){   // pre-reduced, nonzero
  int l=msbp(v); int pos=e.n;
  while(pos>0&&e.lead[pos-1]<l){ e.r[pos]=e.r[pos-1]; e.lead[pos]=e.lead[pos-1]; --pos; }
  e.r[pos]=v; e.lead[pos]=l; e.n+=1;
}

struct Plan {
  unsigned SCOL0[8];      // B_0 thread-bit columns
  unsigned SK16_0[16];    // B_0 reg-bit XOR combos
  unsigned RCOL[12][8];   // exchange g>=1: R thread-bit columns
  unsigned RK16[12][16];  // exchange g>=1: per-k XOR offset (f32x2 units)
  unsigned SRlow[NOUT], SRhigh[NOUT];
  unsigned TM;            // wires (bit positions) touched by B_0 reg cols
  int minnib;             // min achieved nibble rank across exchanges
  bool ok;
};

constexpr Plan make_plan(){
  Plan P{}; P.ok=true; P.minnib=4;
  unsigned cols[12], icols[12];
  for(int p=0;p<12;++p){ cols[p]=1u<<p; icols[p]=1u<<p; }
  unsigned M[NL][12], RM[NL][12], MR[NOUT];
  for(int l=0;l<NL;++l){
    for(int w=0;w<NW;++w){
      int p=NW-1-w;
      M[l][w]=icols[p];
      unsigned r=0; for(int j=0;j<12;++j) r|=((cols[j]>>p)&1u)<<j;
      RM[l][w]=r;
    }
    int rr=(l%(NW-1))+1;
    for(int j=0;j<12;++j) cols[j]=ring_fwd(cols[j],rr);
    unsigned nic[12]={};
    for(int p=0;p<12;++p){
      unsigned y=ring_rev(1u<<p,rr), v=0;
      for(int q=0;q<12;++q) if((y>>q)&1u) v^=icols[q];
      nic[p]=v;
    }
    for(int p=0;p<12;++p) icols[p]=nic[p];
  }
  for(int o=0;o<NOUT;++o){
    int p=NW-1-o; unsigned r=0;
    for(int j=0;j<12;++j) r|=((cols[j]>>p)&1u)<<j;
    MR[o]=r;
  }
  Mat Bprev{}; for(int j=0;j<12;++j) Bprev.col[j]=1u<<j;
  for(int g=0; g<12; ++g){
    int l=g/3, j0=(g%3)*4;
    unsigned mi[4], rmi[4];
    for(int i=0;i<4;++i){ mi[i]=M[l][j0+i]; rmi[i]=RM[l][j0+i]; }
    unsigned Wb[12];
    if(nullspace4(rmi,Wb)!=8){ P.ok=false; return P; }
    unsigned binv[12];
    if(!invert_rows(Bprev,binv)){ P.ok=false; return P; }
    unsigned Vp[8];
    for(int s=0;s<8;++s) Vp[s]=apply_rows(binv,Wb[s]);
    // exhaustive: 4 nibble-independent picks -> lane slots 0..3
    unsigned u[8]={};
    Ech eu{}; Ech en{};
    int nsel=0;
    for(int c=1;c<256 && nsel<4;++c){
      unsigned v=0; for(int a=0;a<8;++a) if((c>>a)&1) v^=Vp[a];
      unsigned vr=ech_red(eu,v); if(!vr) continue;
      unsigned nr=ech_red(en,v&15u); if(!nr) continue;
      ech_add(eu,vr); ech_add(en,nr);
      u[nsel++]=v;
    }
    if(nsel<P.minnib) P.minnib=nsel;
    for(int c=1;c<256 && nsel<8;++c){
      unsigned v=0; for(int a=0;a<8;++a) if((c>>a)&1) v^=Vp[a];
      unsigned vr=ech_red(eu,v); if(!vr) continue;
      ech_add(eu,vr);
      u[nsel++]=v;
    }
    if(nsel!=8){ P.ok=false; return P; }
    Mat Bg{};
    for(int j=0;j<8;++j) Bg.col[j]=apply_cols(Bprev,u[j]);
    for(int i=0;i<4;++i) Bg.col[8+i]=mi[i];
    unsigned tinv[12];
    if(!invert_rows(Bg,tinv)){ P.ok=false; return P; }
    for(int i=0;i<4;++i)
      for(int j=0;j<12;++j){
        int want=(j==8+i)?1:0;
        if((pcnt(Bg.col[j]&rmi[i])&1)!=want){ P.ok=false; return P; }
      }
    if(g==0){
      for(int j=0;j<8;++j) P.SCOL0[j]=Bg.col[j];
      unsigned tm=0;
      for(int k=0;k<16;++k){
        unsigned v=0; for(int i=0;i<4;++i) if((k>>i)&1) v^=Bg.col[8+i];
        P.SK16_0[k]=v; tm|=v;
      }
      P.TM=tm;
    } else {
      for(int j=0;j<8;++j) P.RCOL[g][j]=u[j];
      unsigned rk[4];
      for(int i=0;i<4;++i){
        rk[i]=apply_rows(binv,mi[i]);
        if(apply_cols(Bprev,rk[i])!=mi[i]){ P.ok=false; return P; }
      }
      for(int k=0;k<16;++k){
        unsigned v=0; for(int i=0;i<4;++i) if((k>>i)&1) v^=rk[i];
        P.RK16[g][k]=v;
      }
    }
    Bprev=Bg;
  }
  for(int o=0;o<NOUT;++o){
    unsigned sr=0;
    for(int j=0;j<12;++j) sr|=(unsigned)(pcnt(Bprev.col[j]&MR[o])&1)<<j;
    P.SRlow[o]=sr&255u; P.SRhigh[o]=sr>>8;
  }
  return P;
}

static_assert(make_plan().ok, "basis planning failed");
__device__ constexpr Plan PL = make_plan();

// ======================= device helpers =======================

__device__ __forceinline__ void apply_group(f32x2* a, const float* gw_base, int g){
  #pragma unroll
  for(int i=0;i<4;++i){
    const float* w = gw_base + (g*4+i)*8;
    f32x2 c00={w[0],w[0]}, d00={-w[1],w[1]};
    f32x2 c01={w[2],w[2]}, d01={-w[3],w[3]};
    f32x2 c10={w[4],w[4]}, d10={-w[5],w[5]};
    f32x2 c11={w[6],w[6]}, d11={-w[7],w[7]};
    #pragma unroll
    for(int q=0;q<8;++q){
      const int k0=((q>>i)<<(i+1))|(q&((1<<i)-1));
      const int k1=k0|(1<<i);
      f32x2 a0=a[k0], a1=a[k1];
      f32x2 a0s=a0.yx, a1s=a1.yx;
      f32x2 n0 = c00*a0 + d00*a0s + c01*a1 + d01*a1s;
      f32x2 n1 = c10*a0 + d10*a0s + c11*a1 + d11*a1s;
      a[k0]=n0; a[k1]=n1;
    }
  }
}

__device__ __forceinline__ void gate_coeffs(const float* __restrict__ wts, int gi, float* o){
  const float* w = wts + gi*3;
  float st,ct;  sincosf(0.5f*w[1],&st,&ct);
  float sap,cap; sincosf(0.5f*(w[0]+w[2]),&sap,&cap);
  float sam,cam; sincosf(0.5f*(w[0]-w[2]),&sam,&cam);
  o[0]= cap*ct; o[1]=-sap*ct;
  o[2]=-cam*st; o[3]=-sam*st;
  o[4]= cam*st; o[5]=-sam*st;
  o[6]= cap*ct; o[7]= sap*ct;
}

__global__ void coeff_kernel(const float* __restrict__ wts, float* __restrict__ gws){
  int gi = threadIdx.x;
  if(gi >= NGATE) return;
  float o[8];
  gate_coeffs(wts, gi, o);
  #pragma unroll
  for(int j=0;j<8;++j) gws[gi*8+j]=o[j];
}

// ======================= main kernel =======================

template<bool USE_WS>
__global__ __launch_bounds__(TPB,5)
void vqc_kernel(const float* __restrict__ inp,   // (B,12)
                const float* __restrict__ wts,   // (4,12,3) fallback
                const float* __restrict__ gws,   // (48,8) precomputed
                float* __restrict__ out)         // (B,4)
{
  // 32 KB exactly in USE_WS mode: cs/ss/red alias the amp buffer
  // (disjoint live ranges, barrier-separated).
  constexpr int SMEM_BYTES = DIM*8 + (USE_WS?0:NGATE*8*4);
  __shared__ __align__(16) char smem[SMEM_BYTES];
  f32x2* amp = (f32x2*)smem;
  float* cs  = (float*)smem;         // floats 0..11   (pre-amp phase)
  float* ss  = cs + NW;              // floats 12..23  (pre-amp phase)
  float* red = cs + 2*NW;            // floats 24..39  (post-amp phase)
  float* gtab = (float*)(smem + DIM*8);  // fallback only (non-aliased)

  const int t = threadIdx.x;
  const int b = blockIdx.x;

  if(t < NW){
    float x = inp[b*NW+t];
    float s,c; sincosf(0.78539816339744830962f*x,&s,&c);
    cs[t]=c; ss[t]=s;
  }
  if(!USE_WS && t < NGATE){
    float o[8]; gate_coeffs(wts,t,o);
    #pragma unroll
    for(int j=0;j<8;++j) gtab[t*8+j]=o[j];
  }
  __syncthreads();

  const float* gw = USE_WS ? gws : (const float*)gtab;

  float cr[NW], sr_[NW];
  #pragma unroll
  for(int w=0;w<NW;++w){ cr[w]=cs[w]; sr_[w]=ss[w]; }

  // product-state init in basis B_0: base product over untouched wires,
  // per-k product over wires touched by reg columns (compile-time split).
  unsigned sig_t=0;
  #pragma unroll
  for(int j=0;j<8;++j) sig_t ^= ((t>>j)&1u)? PL.SCOL0[j] : 0u;
  float pbase=1.f;
  #pragma unroll
  for(int p=0;p<12;++p)
    if(!((PL.TM>>p)&1u))
      pbase *= ((sig_t>>p)&1u)? sr_[11-p] : cr[11-p];
  f32x2 a[16];
  #pragma unroll
  for(int k=0;k<16;++k){
    float pk=pbase;
    #pragma unroll
    for(int p=0;p<12;++p)
      if((PL.TM>>p)&1u){
        unsigned bit = ((sig_t ^ PL.SK16_0[k])>>p)&1u;
        pk *= bit? sr_[11-p] : cr[11-p];
      }
    a[k].x=pk; a[k].y=0.f;
  }

  apply_group(a, gw, 0);

  #pragma unroll 1
  for(int g=1; g<12; ++g){
    __syncthreads();                           // prior reads done
    #pragma unroll
    for(int k=0;k<16;++k) amp[k*256+t]=a[k];   // lane-contiguous writes
    __syncthreads();
    unsigned base=0;
    #pragma unroll
    for(int j=0;j<8;++j) base ^= ((t>>j)&1u)? PL.RCOL[g][j] : 0u;
    #pragma unroll
    for(int k=0;k<16;++k) a[k]=amp[base ^ PL.RK16[g][k]];  // rank-4 nibble reads
    apply_group(a, gw, g);
  }

  // expval(PauliZ) wires 0..3 from registers
  float acc[NOUT]={0.f,0.f,0.f,0.f};
  float sg[NOUT];
  #pragma unroll
  for(int o=0;o<NOUT;++o)
    sg[o] = (__popc((unsigned)t & PL.SRlow[o])&1)? -1.f : 1.f;
  #pragma unroll
  for(int k=0;k<16;++k){
    float pr = a[k].x*a[k].x + a[k].y*a[k].y;
    #pragma unroll
    for(int o=0;o<NOUT;++o){
      const bool kp = (pcnt((unsigned)k & PL.SRhigh[o])&1)!=0;  // compile-time
      float f = sg[o]*pr;
      acc[o] += kp ? -f : f;
    }
  }
  #pragma unroll
  for(int o=0;o<NOUT;++o)
    #pragma unroll
    for(int off=32; off>0; off>>=1)
      acc[o] += __shfl_down(acc[o], off);
  __syncthreads();                 // all amp reads done before red aliases it
  const int wv=t>>6, ln=t&63;
  if(ln==0){
    #pragma unroll
    for(int o=0;o<NOUT;++o) red[wv*NOUT+o]=acc[o];
  }
  __syncthreads();
  if(t<NOUT)
    out[b*NOUT+t] = red[0*NOUT+t]+red[1*NOUT+t]+red[2*NOUT+t]+red[3*NOUT+t];
}

// ======================= launch =======================

extern "C" void kernel_launch(void* const* d_in, const int* in_sizes, int n_in,
                              void* d_out, int out_size, void* d_ws, size_t ws_size,
                              hipStream_t stream) {
  const float* inp=(const float*)d_in[0];   // (1024,12) f32
  const float* wts=(const float*)d_in[1];   // (4,12,3) f32
  float* outp=(float*)d_out;                // (1024,4) f32
  const int B = in_sizes[0]/NW;
  if(ws_size >= (size_t)(NGATE*8*sizeof(float))){
    float* gws=(float*)d_ws;
    coeff_kernel<<<1,64,0,stream>>>(wts,gws);
    vqc_kernel<true><<<B,TPB,0,stream>>>(inp,wts,gws,outp);
  } else {
    vqc_kernel<false><<<B,TPB,0,stream>>>(inp,wts,nullptr,outp);
  }
}

// Round 6
// 51.700 us; speedup vs baseline: 1.0363x; 1.0363x over previous
//
#include <hip/hip_runtime.h>

#define NW 12
#define DIM 4096
#define NL 4
#define NGATE 48
#define NOUT 4
#define TPB 256

typedef float f32x2 __attribute__((ext_vector_type(2)));

// ======================= constexpr GF(2) machinery =======================
// State in registers: phys y = k*256 + t (k = 4 reg bits, t = 8 thread bits).
// Per group g (4 gates), basis B_g (storage = B_g(phys)):
//   B_g(e_{8+i}) = m_i          (gate pair masks -> reg bits)
//   cols(B_g) ⊥ rm_i except 8+i (gate role == reg bit, no selects)
// Exchange g-1 -> g: value with old-frame coord y stored at amp[W_g(y)],
// W_g a per-exchange bijection whose 4 nibble rows are rank-4 on BOTH
// S1 = span(lane bits e_0..e_5) and S2 = span(R_g e'_0..e'_5)  ->  both
// write and read lane->bank-pair maps are exactly 4-to-1 (b64 floor).
// W rows found constructively (two-subspace avoidance: x, y, or x^y always
// escapes (F+K1) ∪ (F+K2)); each pick verified before use.

constexpr int pcnt(unsigned x){ return __builtin_popcount(x); }
constexpr int msbp(unsigned x){ return x ? 31-__builtin_clz(x) : -1; }
constexpr unsigned ring_fwd(unsigned x,int r){
  for(int w=0;w<NW;++w){ int c=NW-1-w,t=NW-1-((w+r)%NW); x^=((x>>c)&1u)<<t; } return x;
}
constexpr unsigned ring_rev(unsigned x,int r){
  for(int w=NW-1;w>=0;--w){ int c=NW-1-w,t=NW-1-((w+r)%NW); x^=((x>>c)&1u)<<t; } return x;
}

struct Mat { unsigned col[12]; };
constexpr unsigned apply_cols(const Mat&M, unsigned v){
  unsigned r=0; for(int j=0;j<12;++j) if((v>>j)&1u) r^=M.col[j]; return r;
}
constexpr unsigned apply_rows(const unsigned* rows, unsigned v){
  unsigned r=0; for(int i=0;i<12;++i) r|=(unsigned)(pcnt(rows[i]&v)&1)<<i; return r;
}
constexpr bool invert_rows(const Mat&M, unsigned* ri_out){
  unsigned rb[12]={}, ri[12]={};
  for(int i=0;i<12;++i){ unsigned r=0; for(int j=0;j<12;++j) r|=((M.col[j]>>i)&1u)<<j; rb[i]=r; ri[i]=1u<<i; }
  for(int c=0;c<12;++c){
    int piv=-1; for(int r=c;r<12;++r) if((rb[r]>>c)&1u){piv=r;break;}
    if(piv<0) return false;
    unsigned t=rb[c]; rb[c]=rb[piv]; rb[piv]=t; t=ri[c]; ri[c]=ri[piv]; ri[piv]=t;
    for(int r=0;r<12;++r) if(r!=c&&((rb[r]>>c)&1u)){ rb[r]^=rb[c]; ri[r]^=ri[c]; }
  }
  for(int i=0;i<12;++i) ri_out[i]=ri[i];
  return true;
}
constexpr int nullspace4(const unsigned* A0, unsigned* out){
  unsigned A[4]={}; for(int i=0;i<4;++i) A[i]=A0[i];
  int rank=0; int pivc[4]={-1,-1,-1,-1};
  for(int c=0;c<12&&rank<4;++c){
    int piv=-1; for(int r=rank;r<4;++r) if((A[r]>>c)&1u){piv=r;break;}
    if(piv<0) continue;
    unsigned t=A[rank];A[rank]=A[piv];A[piv]=t;
    for(int r=0;r<4;++r) if(r!=rank&&((A[r]>>c)&1u)) A[r]^=A[rank];
    pivc[rank]=c; ++rank;
  }
  if(rank!=4) return -1;
  bool ispiv[12]={};
  for(int r=0;r<4;++r) ispiv[pivc[r]]=true;
  int cnt=0;
  for(int f=0;f<12;++f) if(!ispiv[f]){
    unsigned v=1u<<f;
    for(int r=0;r<4;++r) if((A[r]>>f)&1u) v|=1u<<pivc[r];
    out[cnt++]=v;
  }
  return cnt;
}
struct Ech { unsigned r[12]; int lead[12]; int n; };
constexpr unsigned ech_red(const Ech&e, unsigned v){
  int mv=msbp(v);
  for(int i=0;i<e.n&&v;++i) if(e.lead[i]==mv){ v^=e.r[i]; mv=msbp(v); }
  return v;
}
constexpr void ech_add(Ech&e, unsigned v){   // pre-reduced, nonzero
  int l=msbp(v); int pos=e.n;
  while(pos>0&&e.lead[pos-1]<l){ e.r[pos]=e.r[pos-1]; e.lead[pos]=e.lead[pos-1]; --pos; }
  e.r[pos]=v; e.lead[pos]=l; e.n+=1;
}

struct Plan {
  unsigned SCOL0[8];      // B_0 thread-bit columns
  unsigned SK16_0[16];    // B_0 reg-bit XOR combos
  unsigned WTC[12][8];    // exchange g: write cols  W(e_j), j=t-bit
  unsigned WK16[12][16];  // exchange g: write k-combos XOR W(e_{8+i})
  unsigned RDC[12][8];    // exchange g: read cols   W(u_j)
  unsigned WRK16[12][16]; // exchange g: read k-combos XOR W(rk_i)
  unsigned SRlow[NOUT], SRhigh[NOUT];
  unsigned TM;            // wires touched by B_0 reg cols
  bool ok;
};

constexpr Plan make_plan(){
  Plan P{}; P.ok=true;
  unsigned cols[12]={}, icols[12]={};
  for(int p=0;p<12;++p){ cols[p]=1u<<p; icols[p]=1u<<p; }
  unsigned M[NL][12]={}, RM[NL][12]={}, MR[NOUT]={};
  for(int l=0;l<NL;++l){
    for(int w=0;w<NW;++w){
      int p=NW-1-w;
      M[l][w]=icols[p];
      unsigned r=0; for(int j=0;j<12;++j) r|=((cols[j]>>p)&1u)<<j;
      RM[l][w]=r;
    }
    int rr=(l%(NW-1))+1;
    for(int j=0;j<12;++j) cols[j]=ring_fwd(cols[j],rr);
    unsigned nic[12]={};
    for(int p=0;p<12;++p){
      unsigned y=ring_rev(1u<<p,rr), v=0;
      for(int q=0;q<12;++q) if((y>>q)&1u) v^=icols[q];
      nic[p]=v;
    }
    for(int p=0;p<12;++p) icols[p]=nic[p];
  }
  for(int o=0;o<NOUT;++o){
    int p=NW-1-o; unsigned r=0;
    for(int j=0;j<12;++j) r|=((cols[j]>>p)&1u)<<j;
    MR[o]=r;
  }
  Mat Bprev{}; for(int j=0;j<12;++j) Bprev.col[j]=1u<<j;
  for(int g=0; g<12; ++g){
    int l=g/3, j0=(g%3)*4;
    unsigned mi[4]={}, rmi[4]={};
    for(int i=0;i<4;++i){ mi[i]=M[l][j0+i]; rmi[i]=RM[l][j0+i]; }
    unsigned u[8]={};
    if(nullspace4(rmi,u)!=8){ P.ok=false; return P; }   // storage-frame null basis
    unsigned binv[12]={};
    if(!invert_rows(Bprev,binv)){ P.ok=false; return P; }
    for(int s=0;s<8;++s) u[s]=apply_rows(binv,u[s]);    // to prev-frame coords
    Mat Bg{};
    for(int j=0;j<8;++j) Bg.col[j]=apply_cols(Bprev,u[j]);
    for(int i=0;i<4;++i) Bg.col[8+i]=mi[i];
    unsigned tinv[12]={};
    if(!invert_rows(Bg,tinv)){ P.ok=false; return P; }
    for(int i=0;i<4;++i)
      for(int j=0;j<12;++j){
        int want=(j==8+i)?1:0;
        if((pcnt(Bg.col[j]&rmi[i])&1)!=want){ P.ok=false; return P; }
      }
    if(g==0){
      for(int j=0;j<8;++j) P.SCOL0[j]=Bg.col[j];
      unsigned tm=0;
      for(int k=0;k<16;++k){
        unsigned v=0; for(int i=0;i<4;++i) if((k>>i)&1) v^=Bg.col[8+i];
        P.SK16_0[k]=v; tm|=v;
      }
      P.TM=tm;
    } else {
      unsigned rk[4]={};
      for(int i=0;i<4;++i){
        rk[i]=apply_rows(binv,mi[i]);
        if(apply_cols(Bprev,rk[i])!=mi[i]){ P.ok=false; return P; }
      }
      // ---- constructive W: 4 rows rank-4 on pi1 (f&63) and pi2 (f vs u_j) ----
      unsigned row2[12]={};                 // pi2 of unit vector b
      for(int bb=0;bb<12;++bb){
        unsigned r=0;
        for(int j=0;j<6;++j) r |= ((u[j]>>bb)&1u) << j;
        row2[bb]=r;
      }
      unsigned rows[12]={}; int nr=0;
      Ech P1{}; Ech P2{}; Ech ER{};
      for(int pick=0;pick<4;++pick){
        int b1=-1;
        for(int bb=0;bb<6;++bb){ if(ech_red(P1, 1u<<bb)){ b1=bb; break; } }
        int b2=-1;
        for(int bb=0;bb<12;++bb){ if(ech_red(P2, row2[bb])){ b2=bb; break; } }
        if(b1<0||b2<0){ P.ok=false; return P; }
        unsigned p2x=row2[b1];
        unsigned p1y=(b2<6)?(1u<<b2):0u;
        unsigned f=0, p1f=0, p2f=0;
        if(ech_red(P2,p2x))      { f=1u<<b1;          p1f=1u<<b1;          p2f=p2x; }
        else if(ech_red(P1,p1y)) { f=1u<<b2;          p1f=p1y;             p2f=row2[b2]; }
        else                     { f=(1u<<b1)^(1u<<b2); p1f=(1u<<b1)^p1y;  p2f=p2x^row2[b2]; }
        unsigned v1=ech_red(P1,p1f), v2=ech_red(P2,p2f);
        if(!v1||!v2){ P.ok=false; return P; }        // proof check
        ech_add(P1,v1); ech_add(P2,v2);
        unsigned vr=ech_red(ER,f);
        if(!vr){ P.ok=false; return P; }
        ech_add(ER,vr);
        rows[nr++]=f;
      }
      for(int bb=0;bb<12 && nr<12;++bb){             // complete basis (units span)
        unsigned vr=ech_red(ER,1u<<bb); if(!vr) continue;
        ech_add(ER,vr); rows[nr++]=1u<<bb;
      }
      if(nr!=12){ P.ok=false; return P; }
      unsigned Wcol[12]={};
      for(int j=0;j<12;++j){
        unsigned v=0;
        for(int i=0;i<12;++i) v |= ((rows[i]>>j)&1u)<<i;
        Wcol[j]=v;
      }
      for(int j=0;j<8;++j){
        P.WTC[g][j]=Wcol[j];
        unsigned v=0;
        for(int q=0;q<12;++q) if((u[j]>>q)&1u) v^=Wcol[q];
        P.RDC[g][j]=v;
      }
      for(int k=0;k<16;++k){
        unsigned wv=0, rv=0;
        for(int i=0;i<4;++i) if((k>>i)&1){
          wv ^= Wcol[8+i];
          unsigned v=0;
          for(int q=0;q<12;++q) if((rk[i]>>q)&1u) v^=Wcol[q];
          rv ^= v;
        }
        P.WK16[g][k]=wv; P.WRK16[g][k]=rv;
      }
    }
    Bprev=Bg;
  }
  for(int o=0;o<NOUT;++o){
    unsigned sr=0;
    for(int j=0;j<12;++j) sr|=(unsigned)(pcnt(Bprev.col[j]&MR[o])&1)<<j;
    P.SRlow[o]=sr&255u; P.SRhigh[o]=sr>>8;
  }
  return P;
}

constexpr Plan PLC = make_plan();        // single constexpr evaluation
static_assert(PLC.ok, "basis/bank planning failed");
__device__ constexpr Plan PL = PLC;      // constant init (copy), no re-eval

// ======================= device helpers =======================

__device__ __forceinline__ void apply_group(f32x2* a, const float* gw_base, int g){
  #pragma unroll
  for(int i=0;i<4;++i){
    const float* w = gw_base + (g*4+i)*8;
    f32x2 c00={w[0],w[0]}, d00={-w[1],w[1]};
    f32x2 c01={w[2],w[2]}, d01={-w[3],w[3]};
    f32x2 c10={w[4],w[4]}, d10={-w[5],w[5]};
    f32x2 c11={w[6],w[6]}, d11={-w[7],w[7]};
    #pragma unroll
    for(int q=0;q<8;++q){
      const int k0=((q>>i)<<(i+1))|(q&((1<<i)-1));
      const int k1=k0|(1<<i);
      f32x2 a0=a[k0], a1=a[k1];
      f32x2 a0s=a0.yx, a1s=a1.yx;
      f32x2 n0 = c00*a0 + d00*a0s + c01*a1 + d01*a1s;
      f32x2 n1 = c10*a0 + d10*a0s + c11*a1 + d11*a1s;
      a[k0]=n0; a[k1]=n1;
    }
  }
}

__device__ __forceinline__ void gate_coeffs(const float* __restrict__ wts, int gi, float* o){
  const float* w = wts + gi*3;
  float st,ct;  sincosf(0.5f*w[1],&st,&ct);
  float sap,cap; sincosf(0.5f*(w[0]+w[2]),&sap,&cap);
  float sam,cam; sincosf(0.5f*(w[0]-w[2]),&sam,&cam);
  o[0]= cap*ct; o[1]=-sap*ct;
  o[2]=-cam*st; o[3]=-sam*st;
  o[4]= cam*st; o[5]=-sam*st;
  o[6]= cap*ct; o[7]= sap*ct;
}

__global__ void coeff_kernel(const float* __restrict__ wts, float* __restrict__ gws){
  int gi = threadIdx.x;
  if(gi >= NGATE) return;
  float o[8];
  gate_coeffs(wts, gi, o);
  #pragma unroll
  for(int j=0;j<8;++j) gws[gi*8+j]=o[j];
}

// ======================= main kernel =======================

template<bool USE_WS>
__global__ __launch_bounds__(TPB,4)
void vqc_kernel(const float* __restrict__ inp,   // (B,12)
                const float* __restrict__ wts,   // (4,12,3) fallback
                const float* __restrict__ gws,   // (48,8) precomputed
                float* __restrict__ out)         // (B,4)
{
  constexpr int SMEM_BYTES = DIM*8 + (USE_WS?0:NGATE*8*4);
  __shared__ __align__(16) char smem[SMEM_BYTES];
  f32x2* amp = (f32x2*)smem;
  float* cs  = (float*)smem;         // floats 0..11   (pre-amp phase)
  float* ss  = cs + NW;              // floats 12..23  (pre-amp phase)
  float* red = cs + 2*NW;            // floats 24..39  (post-amp phase)
  float* gtab = (float*)(smem + DIM*8);  // fallback only

  const int t = threadIdx.x;
  const int b = blockIdx.x;

  if(t < NW){
    float x = inp[b*NW+t];
    float s,c; sincosf(0.78539816339744830962f*x,&s,&c);
    cs[t]=c; ss[t]=s;
  }
  if(!USE_WS && t < NGATE){
    float o[8]; gate_coeffs(wts,t,o);
    #pragma unroll
    for(int j=0;j<8;++j) gtab[t*8+j]=o[j];
  }
  __syncthreads();

  const float* gw = USE_WS ? gws : (const float*)gtab;

  float cr[NW], sr_[NW];
  #pragma unroll
  for(int w=0;w<NW;++w){ cr[w]=cs[w]; sr_[w]=ss[w]; }

  // product-state init in basis B_0
  unsigned sig_t=0;
  #pragma unroll
  for(int j=0;j<8;++j) sig_t ^= ((t>>j)&1u)? PL.SCOL0[j] : 0u;
  float pbase=1.f;
  #pragma unroll
  for(int p=0;p<12;++p)
    if(!((PL.TM>>p)&1u))
      pbase *= ((sig_t>>p)&1u)? sr_[11-p] : cr[11-p];
  f32x2 a[16];
  #pragma unroll
  for(int k=0;k<16;++k){
    float pk=pbase;
    #pragma unroll
    for(int p=0;p<12;++p)
      if((PL.TM>>p)&1u){
        unsigned bit = ((sig_t ^ PL.SK16_0[k])>>p)&1u;
        pk *= bit? sr_[11-p] : cr[11-p];
      }
    a[k].x=pk; a[k].y=0.f;
  }

  apply_group(a, gw, 0);

  #pragma unroll 1
  for(int g=1; g<12; ++g){
    unsigned wb=0, rb=0;
    #pragma unroll
    for(int j=0;j<8;++j){
      wb ^= ((t>>j)&1u)? PL.WTC[g][j] : 0u;
      rb ^= ((t>>j)&1u)? PL.RDC[g][j] : 0u;
    }
    __syncthreads();                           // prior reads done
    #pragma unroll
    for(int k=0;k<16;++k) amp[wb ^ PL.WK16[g][k]] = a[k];   // rank-4 banks
    __syncthreads();
    #pragma unroll
    for(int k=0;k<16;++k) a[k] = amp[rb ^ PL.WRK16[g][k]];  // rank-4 banks
    apply_group(a, gw, g);
  }

  // expval(PauliZ) wires 0..3 from registers
  float acc[NOUT]={0.f,0.f,0.f,0.f};
  float sg[NOUT];
  #pragma unroll
  for(int o=0;o<NOUT;++o)
    sg[o] = (__popc((unsigned)t & PL.SRlow[o])&1)? -1.f : 1.f;
  #pragma unroll
  for(int k=0;k<16;++k){
    float pr = a[k].x*a[k].x + a[k].y*a[k].y;
    #pragma unroll
    for(int o=0;o<NOUT;++o){
      const bool kp = (pcnt((unsigned)k & PL.SRhigh[o])&1)!=0;  // compile-time
      float f = sg[o]*pr;
      acc[o] += kp ? -f : f;
    }
  }
  #pragma unroll
  for(int o=0;o<NOUT;++o)
    #pragma unroll
    for(int off=32; off>0; off>>=1)
      acc[o] += __shfl_down(acc[o], off);
  __syncthreads();                 // all amp reads done before red aliases it
  const int wv=t>>6, ln=t&63;
  if(ln==0){
    #pragma unroll
    for(int o=0;o<NOUT;++o) red[wv*NOUT+o]=acc[o];
  }
  __syncthreads();
  if(t<NOUT)
    out[b*NOUT+t] = red[0*NOUT+t]+red[1*NOUT+t]+red[2*NOUT+t]+red[3*NOUT+t];
}

// ======================= launch =======================

extern "C" void kernel_launch(void* const* d_in, const int* in_sizes, int n_in,
                              void* d_out, int out_size, void* d_ws, size_t ws_size,
                              hipStream_t stream) {
  const float* inp=(const float*)d_in[0];   // (1024,12) f32
  const float* wts=(const float*)d_in[1];   // (4,12,3) f32
  float* outp=(float*)d_out;                // (1024,4) f32
  const int B = in_sizes[0]/NW;
  if(ws_size >= (size_t)(NGATE*8*sizeof(float))){
    float* gws=(float*)d_ws;
    coeff_kernel<<<1,64,0,stream>>>(wts,gws);
    vqc_kernel<true><<<B,TPB,0,stream>>>(inp,wts,gws,outp);
  } else {
    vqc_kernel<false><<<B,TPB,0,stream>>>(inp,wts,nullptr,outp);
  }
}